// Round 7
// baseline (16085.374 us; speedup 1.0000x reference)
//
#include <hip/hip_runtime.h>
#include <hip/hip_bf16.h>
#include <math.h>

// B=512, T=16, DIN=7, D=512, L=2, H=8, HD=64, FF=2048
// R7: rowchain with 256 blocks x 256 threads (4 waves), 2 batch rows/block.
// Zero inter-block sync (rows independent). All 32 blocks per XCD stream the
// SAME weight addresses in near-lockstep -> L2-broadcast instead of the R6
// thrash (R6: 32 blocks x 16 waves = 64 distinct streams/XCD -> 26 GB/s/CU).
// Activations live in LDS; only KV cache (block-private) + out go global.

typedef __attribute__((__ext_vector_type__(8))) short short8;
typedef __attribute__((__ext_vector_type__(4))) float floatx4;

__device__ inline short8 as_short8(uint4 v){ union U{uint4 u; short8 s;} x; x.u=v; return x.s; }

__device__ inline ushort f2bf(float f){
    __hip_bfloat16 h = __float2bfloat16(f);
    ushort u; __builtin_memcpy(&u, &h, 2); return u;
}
__device__ inline float bf2f(ushort u){
    __hip_bfloat16 h; __builtin_memcpy(&h, &u, 2); return __bfloat162float(h);
}

// ---------------------------------------------------------------------------
// Weight swizzle (proven): fp32 W[K][N] -> bf16 16B groups of 8 k-consecutive
// values. Group linear index = (kb*4 + q)*N + n.
// ---------------------------------------------------------------------------
__global__ __launch_bounds__(256)
void swz_k(const float* __restrict__ qkv_w, const float* __restrict__ out_w,
           const float* __restrict__ ff1_w, const float* __restrict__ ff2_w,
           ushort* __restrict__ wsw)
{
    int id = blockIdx.z; int l = id & 1; int mi = id >> 1;
    int K, N; const float* src; size_t doff;
    if (mi == 0)      { K = 512;  N = 1536; src = qkv_w + (size_t)l*786432;  doff = (size_t)l*786432; }
    else if (mi == 1) { K = 512;  N = 512;  src = out_w + (size_t)l*262144;  doff = 1572864 + (size_t)l*262144; }
    else if (mi == 2) { K = 512;  N = 2048; src = ff1_w + (size_t)l*1048576; doff = 2097152 + (size_t)l*1048576; }
    else              { K = 2048; N = 512;  src = ff2_w + (size_t)l*1048576; doff = 4194304 + (size_t)l*1048576; }
    int n0 = blockIdx.x * 64, k0 = blockIdx.y * 32;
    if (n0 >= N || k0 >= K) return;
    __shared__ float tt[32][64];
    int tid = threadIdx.x;
    int c = tid & 63, r = tid >> 6;
    #pragma unroll
    for (int i = 0; i < 8; ++i)
        tt[r + i*4][c] = src[(size_t)(k0 + r + i*4)*N + n0 + c];
    __syncthreads();
    int q = tid >> 6, n = tid & 63;
    union { ushort s[8]; uint4 v; } pk;
    #pragma unroll
    for (int i = 0; i < 8; ++i) pk.s[i] = f2bf(tt[q*8 + i][n]);
    ((uint4*)(wsw + doff))[(size_t)((k0 >> 5)*4 + q)*N + n0 + n] = pk.v;
}

// ---------------------------------------------------------------------------
// rowchain2: 256 blocks x 256 threads; block owns rows {blk*2, blk*2+1}.
// ---------------------------------------------------------------------------
__global__ __launch_bounds__(256)
void rowchain2_k(const float* __restrict__ x, const ushort* __restrict__ wsw,
                 const float* __restrict__ ip_w, const float* __restrict__ ip_b,
                 const float* __restrict__ qkv_b, const float* __restrict__ out_b,
                 const float* __restrict__ ln1_s, const float* __restrict__ ln1_b,
                 const float* __restrict__ ff_b1, const float* __restrict__ ff_b2,
                 const float* __restrict__ ln2_s, const float* __restrict__ ln2_b,
                 const float* __restrict__ hw, const float* __restrict__ hb,
                 float* __restrict__ out,
                 ushort* __restrict__ kc, ushort* __restrict__ vc)
{
    __shared__ uint4  hA[1088];          // 64 octet-groups x 17 (pad), rows 0..15
    __shared__ float  zq[1024];          // 2x512 scratch (q / pre-LN z)
    __shared__ float  hres[1024];        // 2x512 residual stream
    __shared__ __align__(16) ushort ffl[4096];  // 2x2048 relu(ff1) bf16
    __shared__ float  pstat[4][2][2];    // [wave][row][sum,sumsq]
    __shared__ float  stats[2][2];       // [row][mean, rstd]
    __shared__ float  ybc[2][3];

    const int tid  = threadIdx.x;
    const int lane = tid & 63, w = tid >> 6;   // wave 0..3
    const int qd   = lane >> 4, li = lane & 15;
    const int blk  = blockIdx.x;               // 0..255
    const int pm   = tid >> 6;                 // packer row (tid<128): 0..1
    const int pg   = tid & 63;                 // packer octet 0..63
    const int CPL  = 4194304;

    // zero hA once: rows 2..15 of every group stay zero forever
    for (int i = tid; i < 1088; i += 256) hA[i] = make_uint4(0,0,0,0);

    // ---- t=0 embed (rows 0,1): pe(0) -> sin=0 even d, cos=1 odd d
    if (tid < 128){
        int b = blk*2 + pm;
        #pragma unroll
        for (int j = 0; j < 8; ++j){
            int d = pg*8 + j;
            float pe = (d & 1) ? 1.0f : 0.0f;
            float acc = ip_b[d] + pe;
            #pragma unroll
            for (int i = 0; i < 7; ++i)
                acc += x[(b*16 + 0)*7 + i] * ip_w[i*512 + d];
            hres[pm*512 + d] = acc;
        }
    }
    __syncthreads();

    for (int t = 0; t < 16; ++t){
        for (int l = 0; l < 2; ++l){
            // ---- P1a: pack hres -> hA (rows 0,1)
            if (tid < 128){
                union { ushort s[8]; uint4 u; } pk;
                #pragma unroll
                for (int j = 0; j < 8; ++j) pk.s[j] = f2bf(hres[pm*512 + pg*8 + j]);
                hA[pg*17 + pm] = pk.u;
            }
            __syncthreads();

            // ---- P1b: QKV GEMM M=16(2 live) x N=1536, K=512
            {
                const uint4* Bg = (const uint4*)(wsw + (size_t)l*786432);
                const float* qb = qkv_b + l*1536;
                ushort* kcl = kc + (size_t)l*CPL;
                ushort* vcl = vc + (size_t)l*CPL;
                for (int p = 0; p < 4; ++p){
                    floatx4 acc[6] = {};
                    for (int kb = 0; kb < 16; ++kb){
                        short8 af = as_short8(hA[(kb*4 + qd)*17 + li]);
                        #pragma unroll
                        for (int c = 0; c < 6; ++c){
                            int n = (w*24 + p*6 + c)*16 + li;
                            short8 bf = as_short8(Bg[(size_t)(kb*4 + qd)*1536 + n]);
                            acc[c] = __builtin_amdgcn_mfma_f32_16x16x32_bf16(af, bf, acc[c], 0, 0, 0);
                        }
                    }
                    if (qd == 0){
                        #pragma unroll
                        for (int c = 0; c < 6; ++c){
                            #pragma unroll
                            for (int r = 0; r < 2; ++r){
                                int n = (w*24 + p*6 + c)*16 + li;
                                float v = acc[c][r] + qb[n];
                                int b = blk*2 + r;
                                if (n < 512){
                                    zq[r*512 + n] = v;
                                } else if (n < 1024){
                                    int z = n - 512;
                                    kcl[(((size_t)b*8 + (z >> 6))*16 + t)*64 + (z & 63)] = f2bf(v);
                                } else {
                                    int z = n - 1024;
                                    vcl[(((size_t)b*8 + (z >> 6))*16 + t)*64 + (z & 63)] = f2bf(v);
                                }
                            }
                        }
                    }
                }
            }
            __syncthreads();

            // ---- P2: attention, 16 (row,head) pairs, 4 per wave; out -> hA
            {
                const ushort* kcl = kc + (size_t)l*CPL;
                const ushort* vcl = vc + (size_t)l*CPL;
                #pragma unroll
                for (int p = 0; p < 4; ++p){
                    int pair = w*4 + p;
                    int bl = pair >> 3, hh = pair & 7;
                    float qv = zq[bl*512 + hh*64 + lane];
                    const ushort* kp = kcl + (((size_t)(blk*2 + bl)*8 + hh)*16)*64;
                    const ushort* vp = vcl + (((size_t)(blk*2 + bl)*8 + hh)*16)*64;
                    float m_ = -1e30f, s_ = 0.0f, o_ = 0.0f;
                    for (int j = 0; j <= t; ++j){
                        float pq = qv * bf2f(kp[j*64 + lane]);
                        #pragma unroll
                        for (int off = 32; off; off >>= 1) pq += __shfl_xor(pq, off);
                        pq *= 0.125f;
                        float nm = fmaxf(m_, pq);
                        float sc = expf(m_ - nm);
                        float e  = expf(pq - nm);
                        s_ = s_*sc + e;
                        o_ = o_*sc + e*bf2f(vp[j*64 + lane]);
                        m_ = nm;
                    }
                    int g = hh*8 + (lane >> 3);
                    ((ushort*)hA)[(g*17 + bl)*8 + (lane & 7)] = f2bf(o_ / s_);
                }
            }
            __syncthreads();

            // ---- P3: out-proj + bias + resid -> zq, LN1 partials
            {
                const uint4* Bg = (const uint4*)(wsw + 1572864 + (size_t)l*262144);
                const float* ob = out_b + l*512;
                floatx4 acc[8] = {};
                for (int kb = 0; kb < 16; ++kb){
                    short8 af = as_short8(hA[(kb*4 + qd)*17 + li]);
                    #pragma unroll
                    for (int c = 0; c < 8; ++c){
                        int n = (w*8 + c)*16 + li;
                        short8 bf = as_short8(Bg[(size_t)(kb*4 + qd)*512 + n]);
                        acc[c] = __builtin_amdgcn_mfma_f32_16x16x32_bf16(af, bf, acc[c], 0, 0, 0);
                    }
                }
                float ps[2] = {}, pq2[2] = {};
                if (qd == 0){
                    #pragma unroll
                    for (int c = 0; c < 8; ++c){
                        #pragma unroll
                        for (int r = 0; r < 2; ++r){
                            int n = (w*8 + c)*16 + li;
                            float zv = acc[c][r] + ob[n] + hres[r*512 + n];
                            zq[r*512 + n] = zv;
                            ps[r] += zv; pq2[r] += zv*zv;
                        }
                    }
                }
                #pragma unroll
                for (int off = 1; off < 16; off <<= 1){
                    #pragma unroll
                    for (int r = 0; r < 2; ++r){
                        ps[r]  += __shfl_xor(ps[r],  off);
                        pq2[r] += __shfl_xor(pq2[r], off);
                    }
                }
                if (lane == 0){
                    #pragma unroll
                    for (int r = 0; r < 2; ++r){ pstat[w][r][0] = ps[r]; pstat[w][r][1] = pq2[r]; }
                }
            }
            __syncthreads();
            if (tid < 2){
                float s = 0.f, sq = 0.f;
                #pragma unroll
                for (int wv = 0; wv < 4; ++wv){ s += pstat[wv][tid][0]; sq += pstat[wv][tid][1]; }
                float mean = s * (1.0f/512.0f);
                float var  = sq * (1.0f/512.0f) - mean*mean;
                stats[tid][0] = mean; stats[tid][1] = rsqrtf(var + 1e-5f);
            }
            __syncthreads();

            // ---- LN1 apply -> hres + hA pack
            if (tid < 128){
                const float* g1  = ln1_s + l*512;
                const float* be1 = ln1_b + l*512;
                float mean = stats[pm][0], rs = stats[pm][1];
                union { ushort s[8]; uint4 u; } pk;
                #pragma unroll
                for (int j = 0; j < 8; ++j){
                    int d = pg*8 + j;
                    float nv = (zq[pm*512 + d] - mean)*rs*g1[d] + be1[d];
                    hres[pm*512 + d] = nv;
                    pk.s[j] = f2bf(nv);
                }
                hA[pg*17 + pm] = pk.u;
            }
            __syncthreads();

            // ---- P4: FF1 + relu -> ffl (LDS bf16)
            {
                const uint4* Bg = (const uint4*)(wsw + 2097152 + (size_t)l*1048576);
                const float* fb = ff_b1 + l*2048;
                for (int p = 0; p < 4; ++p){
                    floatx4 acc[8] = {};
                    for (int kb = 0; kb < 16; ++kb){
                        short8 af = as_short8(hA[(kb*4 + qd)*17 + li]);
                        #pragma unroll
                        for (int c = 0; c < 8; ++c){
                            int n = (w*32 + p*8 + c)*16 + li;
                            short8 bf = as_short8(Bg[(size_t)(kb*4 + qd)*2048 + n]);
                            acc[c] = __builtin_amdgcn_mfma_f32_16x16x32_bf16(af, bf, acc[c], 0, 0, 0);
                        }
                    }
                    if (qd == 0){
                        #pragma unroll
                        for (int c = 0; c < 8; ++c){
                            #pragma unroll
                            for (int r = 0; r < 2; ++r){
                                int n = (w*32 + p*8 + c)*16 + li;
                                float v = acc[c][r] + fb[n];
                                ffl[r*2048 + n] = f2bf(fmaxf(v, 0.0f));
                            }
                        }
                    }
                }
            }

            // ---- P5: FF2, K=2048 in 4 chunks through hA
            {
                const uint4* Bg = (const uint4*)(wsw + 4194304 + (size_t)l*1048576);
                floatx4 acc[8] = {};
                for (int chunk = 0; chunk < 4; ++chunk){
                    __syncthreads();
                    if (tid < 128)
                        hA[pg*17 + pm] = *(const uint4*)&ffl[pm*2048 + chunk*512 + pg*8];
                    __syncthreads();
                    for (int kb = 0; kb < 16; ++kb){
                        short8 af = as_short8(hA[(kb*4 + qd)*17 + li]);
                        #pragma unroll
                        for (int c = 0; c < 8; ++c){
                            int n = (w*8 + c)*16 + li;
                            short8 bf = as_short8(Bg[(size_t)((chunk*16 + kb)*4 + qd)*512 + n]);
                            acc[c] = __builtin_amdgcn_mfma_f32_16x16x32_bf16(af, bf, acc[c], 0, 0, 0);
                        }
                    }
                }
                const float* fb = ff_b2 + l*512;
                float ps[2] = {}, pq2[2] = {};
                if (qd == 0){
                    #pragma unroll
                    for (int c = 0; c < 8; ++c){
                        #pragma unroll
                        for (int r = 0; r < 2; ++r){
                            int n = (w*8 + c)*16 + li;
                            float zv = acc[c][r] + fb[n] + hres[r*512 + n];
                            zq[r*512 + n] = zv;
                            ps[r] += zv; pq2[r] += zv*zv;
                        }
                    }
                }
                #pragma unroll
                for (int off = 1; off < 16; off <<= 1){
                    #pragma unroll
                    for (int r = 0; r < 2; ++r){
                        ps[r]  += __shfl_xor(ps[r],  off);
                        pq2[r] += __shfl_xor(pq2[r], off);
                    }
                }
                if (lane == 0){
                    #pragma unroll
                    for (int r = 0; r < 2; ++r){ pstat[w][r][0] = ps[r]; pstat[w][r][1] = pq2[r]; }
                }
            }
            __syncthreads();
            if (tid < 2){
                float s = 0.f, sq = 0.f;
                #pragma unroll
                for (int wv = 0; wv < 4; ++wv){ s += pstat[wv][tid][0]; sq += pstat[wv][tid][1]; }
                float mean = s * (1.0f/512.0f);
                float var  = sq * (1.0f/512.0f) - mean*mean;
                stats[tid][0] = mean; stats[tid][1] = rsqrtf(var + 1e-5f);
            }
            __syncthreads();

            // ---- P6: LN2 (+ head + next-t embed when l==1)
            if (l == 0){
                if (tid < 128){
                    const float* g2  = ln2_s + l*512;
                    const float* be2 = ln2_b + l*512;
                    float mean = stats[pm][0], rs = stats[pm][1];
                    #pragma unroll
                    for (int j = 0; j < 8; ++j){
                        int d = pg*8 + j;
                        hres[pm*512 + d] = (zq[pm*512 + d] - mean)*rs*g2[d] + be2[d];
                    }
                }
            } else {
                float nv[8];
                if (tid < 128){
                    const float* g2  = ln2_s + l*512;
                    const float* be2 = ln2_b + l*512;
                    float mean = stats[pm][0], rs = stats[pm][1];
                    float s0 = 0.f, s1 = 0.f, s2 = 0.f;
                    #pragma unroll
                    for (int j = 0; j < 8; ++j){
                        int d = pg*8 + j;
                        nv[j] = (zq[pm*512 + d] - mean)*rs*g2[d] + be2[d];
                        s0 += nv[j]*hw[d*3 + 0];
                        s1 += nv[j]*hw[d*3 + 1];
                        s2 += nv[j]*hw[d*3 + 2];
                    }
                    #pragma unroll
                    for (int off = 32; off; off >>= 1){
                        s0 += __shfl_xor(s0, off);
                        s1 += __shfl_xor(s1, off);
                        s2 += __shfl_xor(s2, off);
                    }
                    if (lane == 0){
                        int b = blk*2 + pm;
                        float y0 = s0 + hb[0], y1 = s1 + hb[1], y2 = s2 + hb[2];
                        out[((size_t)b*16 + t)*3 + 0] = y0;
                        out[((size_t)b*16 + t)*3 + 1] = y1;
                        out[((size_t)b*16 + t)*3 + 2] = y2;
                        ybc[pm][0] = y0; ybc[pm][1] = y1; ybc[pm][2] = y2;
                    }
                }
                __syncthreads();
                if (t < 15 && tid < 128){
                    int b = blk*2 + pm;
                    float y0 = ybc[pm][0], y1 = ybc[pm][1], y2 = ybc[pm][2];
                    #pragma unroll
                    for (int j = 0; j < 8; ++j){
                        int d = pg*8 + j;
                        int e = d & ~1;
                        float div = expf(-(float)e * (9.210340371976184f / 512.0f));
                        float arg = (float)(t + 1) * div;
                        float pe = (d & 1) ? cosf(arg) : sinf(arg);
                        float acc = ip_b[d] + pe;
                        #pragma unroll
                        for (int i = 0; i < 4; ++i)
                            acc += x[((size_t)b*16 + t + 1)*7 + i] * ip_w[i*512 + d];
                        acc += y0*ip_w[4*512 + d] + y1*ip_w[5*512 + d] + y2*ip_w[6*512 + d];
                        hres[pm*512 + d] = acc;
                    }
                }
            }
            __syncthreads();
        }
    }
}

// ---------------------------------------------------------------------------
extern "C" void kernel_launch(void* const* d_in, const int* in_sizes, int n_in,
                              void* d_out, int out_size, void* d_ws, size_t ws_size,
                              hipStream_t stream)
{
    const float* x     = (const float*)d_in[0];
    const float* ip_w  = (const float*)d_in[1];
    const float* ip_b  = (const float*)d_in[2];
    const float* qkv_w = (const float*)d_in[3];
    const float* qkv_b = (const float*)d_in[4];
    const float* out_w = (const float*)d_in[5];
    const float* out_b = (const float*)d_in[6];
    const float* ln1_s = (const float*)d_in[7];
    const float* ln1_b = (const float*)d_in[8];
    const float* ff_w1 = (const float*)d_in[9];
    const float* ff_b1 = (const float*)d_in[10];
    const float* ff_w2 = (const float*)d_in[11];
    const float* ff_b2 = (const float*)d_in[12];
    const float* ln2_s = (const float*)d_in[13];
    const float* ln2_b = (const float*)d_in[14];
    const float* hw    = (const float*)d_in[15];
    const float* hb    = (const float*)d_in[16];
    float* out = (float*)d_out;

    // ws: wsw 12,582,912 B | kc 16 MB | vc 16 MB
    ushort* wsw = (ushort*)d_ws;
    ushort* kc  = (ushort*)((char*)d_ws + 12582912);
    ushort* vc  = kc + 8388608;

    swz_k<<<dim3(32, 64, 8), 256, 0, stream>>>(qkv_w, out_w, ff_w1, ff_w2, wsw);

    rowchain2_k<<<256, 256, 0, stream>>>(
        x, wsw, ip_w, ip_b, qkv_b, out_b, ln1_s, ln1_b,
        ff_b1, ff_b2, ln2_s, ln2_b, hw, hb, out, kc, vc);
}